// Round 4
// baseline (3932.055 us; speedup 1.0000x reference)
//
#include <hip/hip_runtime.h>
#include <math.h>

#define NSAMP 32768      // time-domain samples
#define MH    16384      // half-size complex FFT length
#define LFREQ 32770      // rfft concat(re,im) length = 2*(NSAMP/2+1)
#define NRE   16385      // number of rfft bins
#define NB    64         // batches
#define NA    512        // atoms
#define NITER 64
#define RSTR  32772      // padded row stride for fp32 res/rec in ws

#define KPS    33280     // bf16 row stride = 65*512 (zero-padded past LFREQ)
#define NSLICE 65        // k-slices for dots (512 k each, 128 per wave)
#define USLICE 8         // update kernel k-split
#define NCH    4097      // ceil(LFREQ/8) 8-float chunks per row

typedef __attribute__((ext_vector_type(8))) short bf16x8;
typedef __attribute__((ext_vector_type(8))) unsigned short u16x8;
typedef __attribute__((ext_vector_type(4))) float f32x4;

__device__ __forceinline__ int rev14(int v) { return (int)(__brev((unsigned)v) >> 18); }

__device__ __forceinline__ unsigned short f2bf(float f) {
  unsigned u = __float_as_uint(f);
  u = (u + 0x7fffu + ((u >> 16) & 1u)) >> 16;   // round-to-nearest-even
  return (unsigned short)u;
}
__device__ __forceinline__ float bf2f(unsigned short h) {
  return __uint_as_float(((unsigned)h) << 16);
}

// ---------------- forward rfft: x[b][32768] -> res[b][32770] (re|im concat) ----------------
__global__ __launch_bounds__(1024) void fft_fwd_kernel(const float* __restrict__ x,
                                                       float* __restrict__ res) {
  extern __shared__ float2 s[];   // 16384 complex = 128 KB
  const int b = blockIdx.x, t = threadIdx.x;
  const float2* xrow = (const float2*)(x + (size_t)b * NSAMP);
  for (int m = t; m < MH; m += 1024) s[m] = xrow[rev14(m)];
  __syncthreads();
  for (int st = 1; st <= 14; ++st) {
    const int half = 1 << (st - 1);
    const float fac = 3.14159265358979f / (float)half;
    for (int j = t; j < MH / 2; j += 1024) {
      const int blk = j >> (st - 1), pos = j & (half - 1);
      const int i0 = (blk << st) + pos, i1 = i0 + half;
      float sn, cs; __sincosf(fac * (float)pos, &sn, &cs);
      const float2 u = s[i0], v = s[i1];
      const float tr = cs * v.x + sn * v.y;
      const float ti = cs * v.y - sn * v.x;
      s[i0] = make_float2(u.x + tr, u.y + ti);
      s[i1] = make_float2(u.x - tr, u.y - ti);
    }
    __syncthreads();
  }
  float* rr = res + (size_t)b * RSTR;
  const float fac2 = 6.283185307179586f / (float)NSAMP;
  for (int k = t; k < MH; k += 1024) {
    if (k == 0) {
      const float2 z0 = s[0];
      rr[0] = z0.x + z0.y;      rr[NRE] = 0.f;
      rr[MH] = z0.x - z0.y;     rr[NRE + MH] = 0.f;
    } else {
      const float2 zk = s[k], zm = s[MH - k];
      const float xer = 0.5f * (zk.x + zm.x), xei = 0.5f * (zk.y - zm.y);
      const float p = 0.5f * (zk.y + zm.y);
      const float q = -0.5f * (zk.x - zm.x);
      float sn, cs; __sincosf(fac2 * (float)k, &sn, &cs);
      rr[k]       = xer + cs * p + sn * q;
      rr[NRE + k] = xei + cs * q - sn * p;
    }
  }
}

// ---------------- inverse rfft: rec[b][32770] -> out[b][32768] ----------------
__global__ __launch_bounds__(1024) void fft_inv_kernel(const float* __restrict__ rec,
                                                       float* __restrict__ out) {
  extern __shared__ float2 s[];
  const int b = blockIdx.x, t = threadIdx.x;
  const float* rr = rec + (size_t)b * RSTR;
  const float fac2 = 6.283185307179586f / (float)NSAMP;
  for (int m = t; m < MH; m += 1024) {
    const int k = rev14(m);
    float2 z;
    if (k == 0) {
      const float a0 = rr[0], aM = rr[MH];
      z = make_float2(0.5f * (a0 + aM), 0.5f * (a0 - aM));
    } else {
      const float xr_ = rr[k],       xi_ = rr[NRE + k];
      const float mr  = rr[MH - k],  mi  = rr[NRE + MH - k];
      const float xer = 0.5f * (xr_ + mr), xei = 0.5f * (xi_ - mi);
      const float er  = 0.5f * (xr_ - mr), ei  = 0.5f * (xi_ + mi);
      float sn, cs; __sincosf(fac2 * (float)k, &sn, &cs);
      const float xor_ = cs * er - sn * ei;
      const float xoi  = cs * ei + sn * er;
      z = make_float2(xer - xoi, xei + xor_);
    }
    s[m] = z;
  }
  __syncthreads();
  for (int st = 1; st <= 14; ++st) {
    const int half = 1 << (st - 1);
    const float fac = 3.14159265358979f / (float)half;
    for (int j = t; j < MH / 2; j += 1024) {
      const int blk = j >> (st - 1), pos = j & (half - 1);
      const int i0 = (blk << st) + pos, i1 = i0 + half;
      float sn, cs; __sincosf(fac * (float)pos, &sn, &cs);
      const float2 u = s[i0], v = s[i1];
      const float tr = cs * v.x - sn * v.y;
      const float ti = cs * v.y + sn * v.x;
      s[i0] = make_float2(u.x + tr, u.y + ti);
      s[i1] = make_float2(u.x - tr, u.y - ti);
    }
    __syncthreads();
  }
  const float inv = 1.0f / (float)MH;
  float2* orow = (float2*)(out + (size_t)b * NSAMP);
  for (int m = t; m < MH; m += 1024) {
    const float2 z = s[m];
    orow[m] = make_float2(z.x * inv, z.y * inv);
  }
}

// ---------------- atom norms: rnorm[a] = 1/||atoms[a]|| ----------------
__global__ __launch_bounds__(256) void atom_norm_kernel(const float* __restrict__ atoms,
                                                        float* __restrict__ rnorm) {
  const int a = blockIdx.x, t = threadIdx.x;
  const float2* row2 = (const float2*)(atoms + (size_t)a * LFREQ);
  float ss = 0.f;
  for (int i = t; i < LFREQ / 2; i += 256) {   // 16385 float2 exactly
    const float2 v = row2[i];
    ss += v.x * v.x + v.y * v.y;
  }
  __shared__ float red[256];
  red[t] = ss; __syncthreads();
  for (int st = 128; st > 0; st >>= 1) {
    if (t < st) red[t] += red[t + st];
    __syncthreads();
  }
  if (t == 0) rnorm[a] = 1.0f / sqrtf(red[0]);
}

// ---------------- normalized atoms -> bf16 hi/lo (rnorm folded in), big grid ----------------
__global__ __launch_bounds__(256) void an_bf16_kernel(const float* __restrict__ atoms,
                                                      const float* __restrict__ rnorm,
                                                      unsigned short* __restrict__ anH,
                                                      unsigned short* __restrict__ anL) {
  const int quarter = blockIdx.x;   // 0..3
  const int a = blockIdx.y;
  const int t = threadIdx.x;
  const float rn = rnorm[a];
  const float* row = atoms + (size_t)a * LFREQ;
  unsigned short* hrow = anH + (size_t)a * KPS;
  unsigned short* lrow = anL + (size_t)a * KPS;
  const int c0 = quarter * 1040;
  const int c1 = min(c0 + 1040, KPS / 8);
  for (int c = c0 + t; c < c1; c += 256) {
    const int k0 = c * 8;
    float v[8];
    if (k0 + 8 <= LFREQ) {
      #pragma unroll
      for (int e = 0; e < 4; ++e) {
        const float2 p = *(const float2*)(row + k0 + 2 * e);
        v[2 * e] = p.x; v[2 * e + 1] = p.y;
      }
    } else {
      #pragma unroll
      for (int e = 0; e < 8; ++e) v[e] = (k0 + e < LFREQ) ? row[k0 + e] : 0.f;
    }
    u16x8 hv, lv;
    #pragma unroll
    for (int e = 0; e < 8; ++e) {
      const float sv = v[e] * rn;
      const unsigned short h = f2bf(sv);
      hv[e] = h;
      lv[e] = f2bf(sv - bf2f(h));
    }
    *(u16x8*)(hrow + k0) = hv;
    *(u16x8*)(lrow + k0) = lv;
  }
}

// ---------------- initial res -> bf16 hi/lo ----------------
__global__ __launch_bounds__(256) void res_convert_kernel(const float* __restrict__ res,
                                                          unsigned short* __restrict__ resH,
                                                          unsigned short* __restrict__ resL) {
  const int b = blockIdx.x, t = threadIdx.x;
  const float* row = res + (size_t)b * RSTR;
  unsigned short* hrow = resH + (size_t)b * KPS;
  unsigned short* lrow = resL + (size_t)b * KPS;
  for (int c = t; c < KPS / 8; c += 256) {
    const int k0 = c * 8;
    float v[8];
    if (k0 + 8 <= LFREQ) {
      #pragma unroll
      for (int e = 0; e < 2; ++e) {
        const float4 p = *(const float4*)(row + k0 + 4 * e);
        v[4 * e] = p.x; v[4 * e + 1] = p.y; v[4 * e + 2] = p.z; v[4 * e + 3] = p.w;
      }
    } else {
      #pragma unroll
      for (int e = 0; e < 8; ++e) v[e] = (k0 + e < LFREQ) ? row[k0 + e] : 0.f;
    }
    u16x8 hv, lv;
    #pragma unroll
    for (int e = 0; e < 8; ++e) {
      const unsigned short h = f2bf(v[e]);
      hv[e] = h;
      lv[e] = f2bf(v[e] - bf2f(h));
    }
    *(u16x8*)(hrow + k0) = hv;
    *(u16x8*)(lrow + k0) = lv;
  }
}

// ---------------- dots via split-bf16 MFMA, waves split K; 32 KB LDS reduce ----------------
// partials[s][b][a] = sum_{k in slice s} res[b][k] * an[a][k]
__global__ __launch_bounds__(256, 3) void dots_mfma_kernel(const unsigned short* __restrict__ resH,
                                                           const unsigned short* __restrict__ resL,
                                                           const unsigned short* __restrict__ anH,
                                                           const unsigned short* __restrict__ anL,
                                                           float* __restrict__ partials) {
  __shared__ float lred[2 * 4096];   // 32 KB: two 64x64 partial tiles
  const int slice = blockIdx.x;   // 0..NSLICE-1, 512 k per block
  const int atile = blockIdx.y;   // 0..7, 64 atoms each
  const int t = threadIdx.x;
  const int wv = t >> 6, lane = t & 63;
  const int r16 = lane & 15;      // A row / B col within 16-group
  const int kg  = lane >> 4;      // k-group of 8
  // wave wv owns k-range [slice*512 + wv*128, +128)
  const size_t kbase = (size_t)slice * 512 + (size_t)wv * 128 + (size_t)kg * 8;

  const unsigned short* pAH = resH + (size_t)r16 * KPS + kbase;
  const unsigned short* pAL = resL + (size_t)r16 * KPS + kbase;
  const unsigned short* pBH = anH + (size_t)(atile * 64 + r16) * KPS + kbase;
  const unsigned short* pBL = anL + (size_t)(atile * 64 + r16) * KPS + kbase;

  f32x4 acc[4][4] = {};

  #pragma unroll
  for (int s = 0; s < 4; ++s) {
    const int ko = s * 32;
    bf16x8 aH[4], aL[4], bH[4], bL[4];
    #pragma unroll
    for (int i = 0; i < 4; ++i) {
      aH[i] = *(const bf16x8*)(pAH + (size_t)i * 16 * KPS + ko);
      aL[i] = *(const bf16x8*)(pAL + (size_t)i * 16 * KPS + ko);
    }
    #pragma unroll
    for (int j = 0; j < 4; ++j) {
      bH[j] = *(const bf16x8*)(pBH + (size_t)j * 16 * KPS + ko);
      bL[j] = *(const bf16x8*)(pBL + (size_t)j * 16 * KPS + ko);
    }
    #pragma unroll
    for (int i = 0; i < 4; ++i)
      #pragma unroll
      for (int j = 0; j < 4; ++j) {
        acc[i][j] = __builtin_amdgcn_mfma_f32_16x16x32_bf16(aH[i], bH[j], acc[i][j], 0, 0, 0);
        acc[i][j] = __builtin_amdgcn_mfma_f32_16x16x32_bf16(aH[i], bL[j], acc[i][j], 0, 0, 0);
        acc[i][j] = __builtin_amdgcn_mfma_f32_16x16x32_bf16(aL[i], bH[j], acc[i][j], 0, 0, 0);
      }
  }
  // D layout: row=(lane>>4)*4+e (batch), col=lane&15 (atom)
  const int base = (wv & 1) * 4096;
  if (wv < 2) {
    #pragma unroll
    for (int i = 0; i < 4; ++i)
      #pragma unroll
      for (int j = 0; j < 4; ++j)
        #pragma unroll
        for (int e = 0; e < 4; ++e)
          lred[base + (i * 16 + kg * 4 + e) * 64 + j * 16 + r16] = acc[i][j][e];
  }
  __syncthreads();
  if (wv >= 2) {
    #pragma unroll
    for (int i = 0; i < 4; ++i)
      #pragma unroll
      for (int j = 0; j < 4; ++j)
        #pragma unroll
        for (int e = 0; e < 4; ++e)
          lred[base + (i * 16 + kg * 4 + e) * 64 + j * 16 + r16] += acc[i][j][e];
  }
  __syncthreads();
  for (int o = t; o < 4096; o += 256) {
    const float v = lred[o] + lred[4096 + o];
    partials[((size_t)slice * NB + (o >> 6)) * NA + (size_t)atile * 64 + (o & 63)] = v;
  }
}

// ---------------- fused: per-batch argmax (redundant per k-slice block) + update + bf16 refresh ----------------
__global__ __launch_bounds__(256) void update_kernel(float* __restrict__ res,
                                                     float* __restrict__ rec,
                                                     const float* __restrict__ atoms,
                                                     const float* __restrict__ rnorm,
                                                     const float* __restrict__ partials,
                                                     unsigned short* __restrict__ resH,
                                                     unsigned short* __restrict__ resL,
                                                     float* __restrict__ out2,
                                                     int final_out) {
  const int slice = blockIdx.x;   // 0..USLICE-1
  const int b = blockIdx.y;
  const int t = threadIdx.x;
  // argmax over summed partials for this batch (same fp order in every block -> deterministic)
  __shared__ float sv[256]; __shared__ int si[256];
  float d0 = 0.f, d1 = 0.f;
  for (int s = 0; s < NSLICE; ++s) {
    const float* p = partials + ((size_t)s * NB + b) * NA;
    d0 += p[t];
    d1 += p[t + 256];
  }
  float best = d0; int bi = t;
  if (d1 > best) { best = d1; bi = t + 256; }   // strict > keeps smaller index
  sv[t] = best; si[t] = bi; __syncthreads();
  for (int st = 128; st > 0; st >>= 1) {
    if (t < st) {
      const float v2 = sv[t + st]; const int i2 = si[t + st];
      if (v2 > sv[t] || (v2 == sv[t] && i2 < si[t])) { sv[t] = v2; si[t] = i2; }
    }
    __syncthreads();
  }
  const int idx = si[0];
  const float rn = rnorm[idx];
  const float* arow = atoms + (size_t)idx * LFREQ;
  float* rrow = res + (size_t)b * RSTR;
  float* crow = rec + (size_t)b * RSTR;
  unsigned short* hrow = resH + (size_t)b * KPS;
  unsigned short* lrow = resL + (size_t)b * KPS;
  float* orow = out2 + (size_t)b * LFREQ;
  const int c0 = slice * 513;
  const int c1 = min(c0 + 513, NCH);
  for (int c = c0 + t; c < c1; c += 256) {
    const int k0 = c * 8;
    if (k0 + 8 <= LFREQ) {
      float rv[8], av[8], cv[8];
      #pragma unroll
      for (int e = 0; e < 2; ++e) {
        const float4 q = *(const float4*)(rrow + k0 + 4 * e);
        rv[4 * e] = q.x; rv[4 * e + 1] = q.y; rv[4 * e + 2] = q.z; rv[4 * e + 3] = q.w;
        const float4 qc = *(const float4*)(crow + k0 + 4 * e);
        cv[4 * e] = qc.x; cv[4 * e + 1] = qc.y; cv[4 * e + 2] = qc.z; cv[4 * e + 3] = qc.w;
      }
      #pragma unroll
      for (int e = 0; e < 4; ++e) {
        const float2 p = *(const float2*)(arow + k0 + 2 * e);
        av[2 * e] = p.x; av[2 * e + 1] = p.y;
      }
      float nv[8];
      u16x8 hv, lv;
      #pragma unroll
      for (int e = 0; e < 8; ++e) {
        const float bx = av[e] * rn * rv[e];
        nv[e] = rv[e] - bx;
        cv[e] += bx;
        const unsigned short h = f2bf(nv[e]);
        hv[e] = h;
        lv[e] = f2bf(nv[e] - bf2f(h));
      }
      #pragma unroll
      for (int e = 0; e < 2; ++e) {
        *(float4*)(rrow + k0 + 4 * e) = make_float4(nv[4*e], nv[4*e+1], nv[4*e+2], nv[4*e+3]);
        *(float4*)(crow + k0 + 4 * e) = make_float4(cv[4*e], cv[4*e+1], cv[4*e+2], cv[4*e+3]);
      }
      *(u16x8*)(hrow + k0) = hv;
      *(u16x8*)(lrow + k0) = lv;
      if (final_out) {
        #pragma unroll
        for (int e = 0; e < 2; ++e)
          *(float4*)(orow + k0 + 4 * e) = make_float4(nv[4*e], nv[4*e+1], nv[4*e+2], nv[4*e+3]);
      }
    } else {
      for (int e = 0; e < 8; ++e) {
        const int k = k0 + e;
        if (k < LFREQ) {
          const float r = rrow[k], a = arow[k], cc = crow[k];
          const float bx = a * rn * r;
          const float nx = r - bx;
          rrow[k] = nx;
          crow[k] = cc + bx;
          const unsigned short h = f2bf(nx);
          hrow[k] = h;
          lrow[k] = f2bf(nx - bf2f(h));
          if (final_out) orow[k] = nx;
        }
      }
    }
  }
}

extern "C" void kernel_launch(void* const* d_in, const int* in_sizes, int n_in,
                              void* d_out, int out_size, void* d_ws, size_t ws_size,
                              hipStream_t stream) {
  const float* x = (const float*)d_in[0];      // (64,1,32768)
  const float* atoms = (const float*)d_in[1];  // (1,512,32770)
  float* out = (float*)d_out;

  float* res = (float*)d_ws;                             // 64*32772 f32
  float* rec = res + (size_t)NB * RSTR;                  // 64*32772 f32
  float* rnorm = rec + (size_t)NB * RSTR;                // 512
  float* partials = rnorm + NA;                          // 65*64*512 f32
  unsigned short* resH = (unsigned short*)(partials + (size_t)NSLICE * NB * NA);
  unsigned short* resL = resH + (size_t)NB * KPS;
  unsigned short* anH  = resL + (size_t)NB * KPS;
  unsigned short* anL  = anH + (size_t)NA * KPS;

  hipMemsetAsync(rec, 0, (size_t)NB * RSTR * sizeof(float), stream);
  atom_norm_kernel<<<NA, 256, 0, stream>>>(atoms, rnorm);
  an_bf16_kernel<<<dim3(4, NA), 256, 0, stream>>>(atoms, rnorm, anH, anL);
  fft_fwd_kernel<<<NB, 1024, MH * sizeof(float2), stream>>>(x, res);
  res_convert_kernel<<<NB, 256, 0, stream>>>(res, resH, resL);

  float* res_out = out + (size_t)NB * NSAMP;
  for (int it = 0; it < NITER; ++it) {
    dots_mfma_kernel<<<dim3(NSLICE, 8), 256, 0, stream>>>(resH, resL, anH, anL, partials);
    update_kernel<<<dim3(USLICE, NB), 256, 0, stream>>>(res, rec, atoms, rnorm, partials,
                                                        resH, resL, res_out,
                                                        (it == NITER - 1) ? 1 : 0);
  }

  fft_inv_kernel<<<NB, 1024, MH * sizeof(float2), stream>>>(rec, out);
}

// Round 5
// 3712.037 us; speedup vs baseline: 1.0593x; 1.0593x over previous
//
#include <hip/hip_runtime.h>
#include <math.h>

#define NSAMP 32768      // time-domain samples
#define MH    16384      // half-size complex FFT length
#define LFREQ 32770      // rfft concat(re,im) length = 2*(NSAMP/2+1)
#define NRE   16385      // number of rfft bins
#define NB    64         // batches
#define NA    512        // atoms
#define NITER 64
#define RSTR  32772      // padded row stride for fp32 res/rec in ws

#define KPS    33280     // bf16 row stride = 65*512 (zero-padded past LFREQ)
#define NSLICE 65        // k-slices for dots (512 k each, 128 per wave)
#define USLICE 8         // update kernel k-split
#define NCH    4097      // ceil(LFREQ/8) 8-float chunks per row

typedef __attribute__((ext_vector_type(8))) short bf16x8;
typedef __attribute__((ext_vector_type(8))) unsigned short u16x8;
typedef __attribute__((ext_vector_type(4))) float f32x4;

__device__ __forceinline__ int rev14(int v) { return (int)(__brev((unsigned)v) >> 18); }

__device__ __forceinline__ unsigned short f2bf(float f) {
  unsigned u = __float_as_uint(f);
  u = (u + 0x7fffu + ((u >> 16) & 1u)) >> 16;   // round-to-nearest-even
  return (unsigned short)u;
}
__device__ __forceinline__ float bf2f(unsigned short h) {
  return __uint_as_float(((unsigned)h) << 16);
}

// ---------------- forward rfft: x[b][32768] -> res[b][32770] (re|im concat) ----------------
__global__ __launch_bounds__(1024) void fft_fwd_kernel(const float* __restrict__ x,
                                                       float* __restrict__ res) {
  extern __shared__ float2 s[];   // 16384 complex = 128 KB
  const int b = blockIdx.x, t = threadIdx.x;
  const float2* xrow = (const float2*)(x + (size_t)b * NSAMP);
  for (int m = t; m < MH; m += 1024) s[m] = xrow[rev14(m)];
  __syncthreads();
  for (int st = 1; st <= 14; ++st) {
    const int half = 1 << (st - 1);
    const float fac = 3.14159265358979f / (float)half;
    for (int j = t; j < MH / 2; j += 1024) {
      const int blk = j >> (st - 1), pos = j & (half - 1);
      const int i0 = (blk << st) + pos, i1 = i0 + half;
      float sn, cs; __sincosf(fac * (float)pos, &sn, &cs);
      const float2 u = s[i0], v = s[i1];
      const float tr = cs * v.x + sn * v.y;
      const float ti = cs * v.y - sn * v.x;
      s[i0] = make_float2(u.x + tr, u.y + ti);
      s[i1] = make_float2(u.x - tr, u.y - ti);
    }
    __syncthreads();
  }
  float* rr = res + (size_t)b * RSTR;
  const float fac2 = 6.283185307179586f / (float)NSAMP;
  for (int k = t; k < MH; k += 1024) {
    if (k == 0) {
      const float2 z0 = s[0];
      rr[0] = z0.x + z0.y;      rr[NRE] = 0.f;
      rr[MH] = z0.x - z0.y;     rr[NRE + MH] = 0.f;
    } else {
      const float2 zk = s[k], zm = s[MH - k];
      const float xer = 0.5f * (zk.x + zm.x), xei = 0.5f * (zk.y - zm.y);
      const float p = 0.5f * (zk.y + zm.y);
      const float q = -0.5f * (zk.x - zm.x);
      float sn, cs; __sincosf(fac2 * (float)k, &sn, &cs);
      rr[k]       = xer + cs * p + sn * q;
      rr[NRE + k] = xei + cs * q - sn * p;
    }
  }
}

// ---------------- inverse rfft: rec[b][32770] -> out[b][32768] ----------------
__global__ __launch_bounds__(1024) void fft_inv_kernel(const float* __restrict__ rec,
                                                       float* __restrict__ out) {
  extern __shared__ float2 s[];
  const int b = blockIdx.x, t = threadIdx.x;
  const float* rr = rec + (size_t)b * RSTR;
  const float fac2 = 6.283185307179586f / (float)NSAMP;
  for (int m = t; m < MH; m += 1024) {
    const int k = rev14(m);
    float2 z;
    if (k == 0) {
      const float a0 = rr[0], aM = rr[MH];
      z = make_float2(0.5f * (a0 + aM), 0.5f * (a0 - aM));
    } else {
      const float xr_ = rr[k],       xi_ = rr[NRE + k];
      const float mr  = rr[MH - k],  mi  = rr[NRE + MH - k];
      const float xer = 0.5f * (xr_ + mr), xei = 0.5f * (xi_ - mi);
      const float er  = 0.5f * (xr_ - mr), ei  = 0.5f * (xi_ + mi);
      float sn, cs; __sincosf(fac2 * (float)k, &sn, &cs);
      const float xor_ = cs * er - sn * ei;
      const float xoi  = cs * ei + sn * er;
      z = make_float2(xer - xoi, xei + xor_);
    }
    s[m] = z;
  }
  __syncthreads();
  for (int st = 1; st <= 14; ++st) {
    const int half = 1 << (st - 1);
    const float fac = 3.14159265358979f / (float)half;
    for (int j = t; j < MH / 2; j += 1024) {
      const int blk = j >> (st - 1), pos = j & (half - 1);
      const int i0 = (blk << st) + pos, i1 = i0 + half;
      float sn, cs; __sincosf(fac * (float)pos, &sn, &cs);
      const float2 u = s[i0], v = s[i1];
      const float tr = cs * v.x - sn * v.y;
      const float ti = cs * v.y + sn * v.x;
      s[i0] = make_float2(u.x + tr, u.y + ti);
      s[i1] = make_float2(u.x - tr, u.y - ti);
    }
    __syncthreads();
  }
  const float inv = 1.0f / (float)MH;
  float2* orow = (float2*)(out + (size_t)b * NSAMP);
  for (int m = t; m < MH; m += 1024) {
    const float2 z = s[m];
    orow[m] = make_float2(z.x * inv, z.y * inv);
  }
}

// ---------------- atom norms: rnorm[a] = 1/||atoms[a]|| ----------------
__global__ __launch_bounds__(256) void atom_norm_kernel(const float* __restrict__ atoms,
                                                        float* __restrict__ rnorm) {
  const int a = blockIdx.x, t = threadIdx.x;
  const float2* row2 = (const float2*)(atoms + (size_t)a * LFREQ);
  float ss = 0.f;
  for (int i = t; i < LFREQ / 2; i += 256) {   // 16385 float2 exactly
    const float2 v = row2[i];
    ss += v.x * v.x + v.y * v.y;
  }
  __shared__ float red[256];
  red[t] = ss; __syncthreads();
  for (int st = 128; st > 0; st >>= 1) {
    if (t < st) red[t] += red[t + st];
    __syncthreads();
  }
  if (t == 0) rnorm[a] = 1.0f / sqrtf(red[0]);
}

// ---------------- normalized atoms -> bf16 hi/lo (rnorm folded in), big grid ----------------
__global__ __launch_bounds__(256) void an_bf16_kernel(const float* __restrict__ atoms,
                                                      const float* __restrict__ rnorm,
                                                      unsigned short* __restrict__ anH,
                                                      unsigned short* __restrict__ anL) {
  const int quarter = blockIdx.x;   // 0..3
  const int a = blockIdx.y;
  const int t = threadIdx.x;
  const float rn = rnorm[a];
  const float* row = atoms + (size_t)a * LFREQ;
  unsigned short* hrow = anH + (size_t)a * KPS;
  unsigned short* lrow = anL + (size_t)a * KPS;
  const int c0 = quarter * 1040;
  const int c1 = min(c0 + 1040, KPS / 8);
  for (int c = c0 + t; c < c1; c += 256) {
    const int k0 = c * 8;
    float v[8];
    if (k0 + 8 <= LFREQ) {
      #pragma unroll
      for (int e = 0; e < 4; ++e) {
        const float2 p = *(const float2*)(row + k0 + 2 * e);
        v[2 * e] = p.x; v[2 * e + 1] = p.y;
      }
    } else {
      #pragma unroll
      for (int e = 0; e < 8; ++e) v[e] = (k0 + e < LFREQ) ? row[k0 + e] : 0.f;
    }
    u16x8 hv, lv;
    #pragma unroll
    for (int e = 0; e < 8; ++e) {
      const float sv = v[e] * rn;
      const unsigned short h = f2bf(sv);
      hv[e] = h;
      lv[e] = f2bf(sv - bf2f(h));
    }
    *(u16x8*)(hrow + k0) = hv;
    *(u16x8*)(lrow + k0) = lv;
  }
}

// ---------------- initial res -> bf16 hi/lo ----------------
__global__ __launch_bounds__(256) void res_convert_kernel(const float* __restrict__ res,
                                                          unsigned short* __restrict__ resH,
                                                          unsigned short* __restrict__ resL) {
  const int b = blockIdx.x, t = threadIdx.x;
  const float* row = res + (size_t)b * RSTR;
  unsigned short* hrow = resH + (size_t)b * KPS;
  unsigned short* lrow = resL + (size_t)b * KPS;
  for (int c = t; c < KPS / 8; c += 256) {
    const int k0 = c * 8;
    float v[8];
    if (k0 + 8 <= LFREQ) {
      #pragma unroll
      for (int e = 0; e < 2; ++e) {
        const float4 p = *(const float4*)(row + k0 + 4 * e);
        v[4 * e] = p.x; v[4 * e + 1] = p.y; v[4 * e + 2] = p.z; v[4 * e + 3] = p.w;
      }
    } else {
      #pragma unroll
      for (int e = 0; e < 8; ++e) v[e] = (k0 + e < LFREQ) ? row[k0 + e] : 0.f;
    }
    u16x8 hv, lv;
    #pragma unroll
    for (int e = 0; e < 8; ++e) {
      const unsigned short h = f2bf(v[e]);
      hv[e] = h;
      lv[e] = f2bf(v[e] - bf2f(h));
    }
    *(u16x8*)(hrow + k0) = hv;
    *(u16x8*)(lrow + k0) = lv;
  }
}

// ---------------- dots via split-bf16 MFMA, waves split K; 32 KB LDS reduce ----------------
// partials[s][b][a] = sum_{k in slice s} res[b][k] * an[a][k]
__global__ __launch_bounds__(256) void dots_mfma_kernel(const unsigned short* __restrict__ resH,
                                                        const unsigned short* __restrict__ resL,
                                                        const unsigned short* __restrict__ anH,
                                                        const unsigned short* __restrict__ anL,
                                                        float* __restrict__ partials) {
  __shared__ float lred[2 * 4096];   // 32 KB: two 64x64 partial tiles
  const int slice = blockIdx.x;   // 0..NSLICE-1, 512 k per block
  const int atile = blockIdx.y;   // 0..7, 64 atoms each
  const int t = threadIdx.x;
  const int wv = t >> 6, lane = t & 63;
  const int r16 = lane & 15;      // A row / B col within 16-group
  const int kg  = lane >> 4;      // k-group of 8
  // wave wv owns k-range [slice*512 + wv*128, +128)
  const size_t kbase = (size_t)slice * 512 + (size_t)wv * 128 + (size_t)kg * 8;

  const unsigned short* pAH = resH + (size_t)r16 * KPS + kbase;
  const unsigned short* pAL = resL + (size_t)r16 * KPS + kbase;
  const unsigned short* pBH = anH + (size_t)(atile * 64 + r16) * KPS + kbase;
  const unsigned short* pBL = anL + (size_t)(atile * 64 + r16) * KPS + kbase;

  f32x4 acc[4][4] = {};

  #pragma unroll
  for (int s = 0; s < 4; ++s) {
    const int ko = s * 32;
    bf16x8 aH[4], aL[4], bH[4], bL[4];
    #pragma unroll
    for (int i = 0; i < 4; ++i) {
      aH[i] = *(const bf16x8*)(pAH + (size_t)i * 16 * KPS + ko);
      aL[i] = *(const bf16x8*)(pAL + (size_t)i * 16 * KPS + ko);
    }
    #pragma unroll
    for (int j = 0; j < 4; ++j) {
      bH[j] = *(const bf16x8*)(pBH + (size_t)j * 16 * KPS + ko);
      bL[j] = *(const bf16x8*)(pBL + (size_t)j * 16 * KPS + ko);
    }
    #pragma unroll
    for (int i = 0; i < 4; ++i)
      #pragma unroll
      for (int j = 0; j < 4; ++j) {
        acc[i][j] = __builtin_amdgcn_mfma_f32_16x16x32_bf16(aH[i], bH[j], acc[i][j], 0, 0, 0);
        acc[i][j] = __builtin_amdgcn_mfma_f32_16x16x32_bf16(aH[i], bL[j], acc[i][j], 0, 0, 0);
        acc[i][j] = __builtin_amdgcn_mfma_f32_16x16x32_bf16(aL[i], bH[j], acc[i][j], 0, 0, 0);
      }
  }
  // D layout: row=(lane>>4)*4+e (batch), col=lane&15 (atom)
  const int base = (wv & 1) * 4096;
  if (wv < 2) {
    #pragma unroll
    for (int i = 0; i < 4; ++i)
      #pragma unroll
      for (int j = 0; j < 4; ++j)
        #pragma unroll
        for (int e = 0; e < 4; ++e)
          lred[base + (i * 16 + kg * 4 + e) * 64 + j * 16 + r16] = acc[i][j][e];
  }
  __syncthreads();
  if (wv >= 2) {
    #pragma unroll
    for (int i = 0; i < 4; ++i)
      #pragma unroll
      for (int j = 0; j < 4; ++j)
        #pragma unroll
        for (int e = 0; e < 4; ++e)
          lred[base + (i * 16 + kg * 4 + e) * 64 + j * 16 + r16] += acc[i][j][e];
  }
  __syncthreads();
  for (int o = t; o < 4096; o += 256) {
    const float v = lred[o] + lred[4096 + o];
    partials[((size_t)slice * NB + (o >> 6)) * NA + (size_t)atile * 64 + (o & 63)] = v;
  }
}

// ---------------- reduce partials over slices + argmax (once per batch) ----------------
__global__ __launch_bounds__(256) void reduce_argmax_kernel(const float* __restrict__ partials,
                                                            int* __restrict__ bestidx) {
  const int b = blockIdx.x, t = threadIdx.x;
  float d0 = 0.f, d1 = 0.f;
  for (int s = 0; s < NSLICE; ++s) {
    const float* p = partials + ((size_t)s * NB + b) * NA;
    d0 += p[t];
    d1 += p[t + 256];
  }
  float best = d0; int bi = t;
  if (d1 > best) { best = d1; bi = t + 256; }   // strict > keeps smaller index
  __shared__ float sv[256]; __shared__ int si[256];
  sv[t] = best; si[t] = bi; __syncthreads();
  for (int st = 128; st > 0; st >>= 1) {
    if (t < st) {
      const float v2 = sv[t + st]; const int i2 = si[t + st];
      if (v2 > sv[t] || (v2 == sv[t] && i2 < si[t])) { sv[t] = v2; si[t] = i2; }
    }
    __syncthreads();
  }
  if (t == 0) bestidx[b] = si[0];
}

// ---------------- res/rec update + res bf16 refresh (vectorized); final iter also writes out2 ----------------
__global__ __launch_bounds__(256) void update_kernel(float* __restrict__ res,
                                                     float* __restrict__ rec,
                                                     const float* __restrict__ atoms,
                                                     const float* __restrict__ rnorm,
                                                     const int* __restrict__ bestidx,
                                                     unsigned short* __restrict__ resH,
                                                     unsigned short* __restrict__ resL,
                                                     float* __restrict__ out2,
                                                     int final_out) {
  const int slice = blockIdx.x;   // 0..USLICE-1
  const int b = blockIdx.y;
  const int t = threadIdx.x;
  const int idx = bestidx[b];
  const float rn = rnorm[idx];
  const float* arow = atoms + (size_t)idx * LFREQ;
  float* rrow = res + (size_t)b * RSTR;
  float* crow = rec + (size_t)b * RSTR;
  unsigned short* hrow = resH + (size_t)b * KPS;
  unsigned short* lrow = resL + (size_t)b * KPS;
  float* orow = out2 + (size_t)b * LFREQ;
  const int c0 = slice * 513;
  const int c1 = min(c0 + 513, NCH);
  for (int c = c0 + t; c < c1; c += 256) {
    const int k0 = c * 8;
    if (k0 + 8 <= LFREQ) {
      float rv[8], av[8], cv[8];
      #pragma unroll
      for (int e = 0; e < 2; ++e) {
        const float4 q = *(const float4*)(rrow + k0 + 4 * e);
        rv[4 * e] = q.x; rv[4 * e + 1] = q.y; rv[4 * e + 2] = q.z; rv[4 * e + 3] = q.w;
        const float4 qc = *(const float4*)(crow + k0 + 4 * e);
        cv[4 * e] = qc.x; cv[4 * e + 1] = qc.y; cv[4 * e + 2] = qc.z; cv[4 * e + 3] = qc.w;
      }
      #pragma unroll
      for (int e = 0; e < 4; ++e) {
        const float2 p = *(const float2*)(arow + k0 + 2 * e);
        av[2 * e] = p.x; av[2 * e + 1] = p.y;
      }
      float nv[8];
      u16x8 hv, lv;
      #pragma unroll
      for (int e = 0; e < 8; ++e) {
        const float bx = av[e] * rn * rv[e];
        nv[e] = rv[e] - bx;
        cv[e] += bx;
        const unsigned short h = f2bf(nv[e]);
        hv[e] = h;
        lv[e] = f2bf(nv[e] - bf2f(h));
      }
      #pragma unroll
      for (int e = 0; e < 2; ++e) {
        *(float4*)(rrow + k0 + 4 * e) = make_float4(nv[4*e], nv[4*e+1], nv[4*e+2], nv[4*e+3]);
        *(float4*)(crow + k0 + 4 * e) = make_float4(cv[4*e], cv[4*e+1], cv[4*e+2], cv[4*e+3]);
      }
      *(u16x8*)(hrow + k0) = hv;
      *(u16x8*)(lrow + k0) = lv;
      if (final_out) {
        #pragma unroll
        for (int e = 0; e < 2; ++e)
          *(float4*)(orow + k0 + 4 * e) = make_float4(nv[4*e], nv[4*e+1], nv[4*e+2], nv[4*e+3]);
      }
    } else {
      for (int e = 0; e < 8; ++e) {
        const int k = k0 + e;
        if (k < LFREQ) {
          const float r = rrow[k], a = arow[k], cc = crow[k];
          const float bx = a * rn * r;
          const float nx = r - bx;
          rrow[k] = nx;
          crow[k] = cc + bx;
          const unsigned short h = f2bf(nx);
          hrow[k] = h;
          lrow[k] = f2bf(nx - bf2f(h));
          if (final_out) orow[k] = nx;
        }
      }
    }
  }
}

extern "C" void kernel_launch(void* const* d_in, const int* in_sizes, int n_in,
                              void* d_out, int out_size, void* d_ws, size_t ws_size,
                              hipStream_t stream) {
  const float* x = (const float*)d_in[0];      // (64,1,32768)
  const float* atoms = (const float*)d_in[1];  // (1,512,32770)
  float* out = (float*)d_out;

  float* res = (float*)d_ws;                             // 64*32772 f32
  float* rec = res + (size_t)NB * RSTR;                  // 64*32772 f32
  float* rnorm = rec + (size_t)NB * RSTR;                // 512
  float* partials = rnorm + NA;                          // 65*64*512 f32
  int* bestidx = (int*)(partials + (size_t)NSLICE * NB * NA);   // 64
  unsigned short* resH = (unsigned short*)(bestidx + 64);
  unsigned short* resL = resH + (size_t)NB * KPS;
  unsigned short* anH  = resL + (size_t)NB * KPS;
  unsigned short* anL  = anH + (size_t)NA * KPS;

  hipMemsetAsync(rec, 0, (size_t)NB * RSTR * sizeof(float), stream);
  atom_norm_kernel<<<NA, 256, 0, stream>>>(atoms, rnorm);
  an_bf16_kernel<<<dim3(4, NA), 256, 0, stream>>>(atoms, rnorm, anH, anL);
  fft_fwd_kernel<<<NB, 1024, MH * sizeof(float2), stream>>>(x, res);
  res_convert_kernel<<<NB, 256, 0, stream>>>(res, resH, resL);

  float* res_out = out + (size_t)NB * NSAMP;
  for (int it = 0; it < NITER; ++it) {
    dots_mfma_kernel<<<dim3(NSLICE, 8), 256, 0, stream>>>(resH, resL, anH, anL, partials);
    reduce_argmax_kernel<<<NB, 256, 0, stream>>>(partials, bestidx);
    update_kernel<<<dim3(USLICE, NB), 256, 0, stream>>>(res, rec, atoms, rnorm, bestidx,
                                                        resH, resL, res_out,
                                                        (it == NITER - 1) ? 1 : 0);
  }

  fft_inv_kernel<<<NB, 1024, MH * sizeof(float2), stream>>>(rec, out);
}

// Round 6
// 3126.986 us; speedup vs baseline: 1.2575x; 1.1871x over previous
//
#include <hip/hip_runtime.h>
#include <math.h>

#define NSAMP 32768      // time-domain samples
#define MH    16384      // half-size complex FFT length
#define LFREQ 32770      // rfft concat(re,im) length = 2*(NSAMP/2+1)
#define NRE   16385      // number of rfft bins
#define NB    64         // batches
#define NA    512        // atoms
#define NITER 64
#define RSTR  32772      // padded row stride for fp32 res/rec in ws

#define KPS    33280     // bf16 row stride = 65*512 (zero-padded past LFREQ)
#define NSLICE 65        // k-slices for dots (512 k each)
#define USLICE 8         // update kernel k-split
#define NCH    4097      // ceil(LFREQ/8) 8-float chunks per row

typedef __attribute__((ext_vector_type(8))) short bf16x8;
typedef __attribute__((ext_vector_type(8))) unsigned short u16x8;
typedef __attribute__((ext_vector_type(4))) float f32x4;

__device__ __forceinline__ int rev14(int v) { return (int)(__brev((unsigned)v) >> 18); }

__device__ __forceinline__ unsigned short f2bf(float f) {
  unsigned u = __float_as_uint(f);
  u = (u + 0x7fffu + ((u >> 16) & 1u)) >> 16;   // round-to-nearest-even
  return (unsigned short)u;
}
__device__ __forceinline__ float bf2f(unsigned short h) {
  return __uint_as_float(((unsigned)h) << 16);
}

// ---------------- forward rfft: x[b][32768] -> res[b][32770] (re|im concat) ----------------
__global__ __launch_bounds__(1024) void fft_fwd_kernel(const float* __restrict__ x,
                                                       float* __restrict__ res) {
  extern __shared__ float2 s[];   // 16384 complex = 128 KB
  const int b = blockIdx.x, t = threadIdx.x;
  const float2* xrow = (const float2*)(x + (size_t)b * NSAMP);
  for (int m = t; m < MH; m += 1024) s[m] = xrow[rev14(m)];
  __syncthreads();
  for (int st = 1; st <= 14; ++st) {
    const int half = 1 << (st - 1);
    const float fac = 3.14159265358979f / (float)half;
    for (int j = t; j < MH / 2; j += 1024) {
      const int blk = j >> (st - 1), pos = j & (half - 1);
      const int i0 = (blk << st) + pos, i1 = i0 + half;
      float sn, cs; __sincosf(fac * (float)pos, &sn, &cs);
      const float2 u = s[i0], v = s[i1];
      const float tr = cs * v.x + sn * v.y;
      const float ti = cs * v.y - sn * v.x;
      s[i0] = make_float2(u.x + tr, u.y + ti);
      s[i1] = make_float2(u.x - tr, u.y - ti);
    }
    __syncthreads();
  }
  float* rr = res + (size_t)b * RSTR;
  const float fac2 = 6.283185307179586f / (float)NSAMP;
  for (int k = t; k < MH; k += 1024) {
    if (k == 0) {
      const float2 z0 = s[0];
      rr[0] = z0.x + z0.y;      rr[NRE] = 0.f;
      rr[MH] = z0.x - z0.y;     rr[NRE + MH] = 0.f;
    } else {
      const float2 zk = s[k], zm = s[MH - k];
      const float xer = 0.5f * (zk.x + zm.x), xei = 0.5f * (zk.y - zm.y);
      const float p = 0.5f * (zk.y + zm.y);
      const float q = -0.5f * (zk.x - zm.x);
      float sn, cs; __sincosf(fac2 * (float)k, &sn, &cs);
      rr[k]       = xer + cs * p + sn * q;
      rr[NRE + k] = xei + cs * q - sn * p;
    }
  }
}

// ---------------- inverse rfft: rec[b][32770] -> out[b][32768] ----------------
__global__ __launch_bounds__(1024) void fft_inv_kernel(const float* __restrict__ rec,
                                                       float* __restrict__ out) {
  extern __shared__ float2 s[];
  const int b = blockIdx.x, t = threadIdx.x;
  const float* rr = rec + (size_t)b * RSTR;
  const float fac2 = 6.283185307179586f / (float)NSAMP;
  for (int m = t; m < MH; m += 1024) {
    const int k = rev14(m);
    float2 z;
    if (k == 0) {
      const float a0 = rr[0], aM = rr[MH];
      z = make_float2(0.5f * (a0 + aM), 0.5f * (a0 - aM));
    } else {
      const float xr_ = rr[k],       xi_ = rr[NRE + k];
      const float mr  = rr[MH - k],  mi  = rr[NRE + MH - k];
      const float xer = 0.5f * (xr_ + mr), xei = 0.5f * (xi_ - mi);
      const float er  = 0.5f * (xr_ - mr), ei  = 0.5f * (xi_ + mi);
      float sn, cs; __sincosf(fac2 * (float)k, &sn, &cs);
      const float xor_ = cs * er - sn * ei;
      const float xoi  = cs * ei + sn * er;
      z = make_float2(xer - xoi, xei + xor_);
    }
    s[m] = z;
  }
  __syncthreads();
  for (int st = 1; st <= 14; ++st) {
    const int half = 1 << (st - 1);
    const float fac = 3.14159265358979f / (float)half;
    for (int j = t; j < MH / 2; j += 1024) {
      const int blk = j >> (st - 1), pos = j & (half - 1);
      const int i0 = (blk << st) + pos, i1 = i0 + half;
      float sn, cs; __sincosf(fac * (float)pos, &sn, &cs);
      const float2 u = s[i0], v = s[i1];
      const float tr = cs * v.x - sn * v.y;
      const float ti = cs * v.y + sn * v.x;
      s[i0] = make_float2(u.x + tr, u.y + ti);
      s[i1] = make_float2(u.x - tr, u.y - ti);
    }
    __syncthreads();
  }
  const float inv = 1.0f / (float)MH;
  float2* orow = (float2*)(out + (size_t)b * NSAMP);
  for (int m = t; m < MH; m += 1024) {
    const float2 z = s[m];
    orow[m] = make_float2(z.x * inv, z.y * inv);
  }
}

// ---------------- atom norms: rnorm[a] = 1/||atoms[a]|| ----------------
__global__ __launch_bounds__(256) void atom_norm_kernel(const float* __restrict__ atoms,
                                                        float* __restrict__ rnorm) {
  const int a = blockIdx.x, t = threadIdx.x;
  const float2* row2 = (const float2*)(atoms + (size_t)a * LFREQ);
  float ss = 0.f;
  for (int i = t; i < LFREQ / 2; i += 256) {   // 16385 float2 exactly
    const float2 v = row2[i];
    ss += v.x * v.x + v.y * v.y;
  }
  __shared__ float red[256];
  red[t] = ss; __syncthreads();
  for (int st = 128; st > 0; st >>= 1) {
    if (t < st) red[t] += red[t + st];
    __syncthreads();
  }
  if (t == 0) rnorm[a] = 1.0f / sqrtf(red[0]);
}

// ---------------- normalized atoms -> bf16 hi/lo (rnorm folded in), big grid ----------------
__global__ __launch_bounds__(256) void an_bf16_kernel(const float* __restrict__ atoms,
                                                      const float* __restrict__ rnorm,
                                                      unsigned short* __restrict__ anH,
                                                      unsigned short* __restrict__ anL) {
  const int quarter = blockIdx.x;   // 0..3
  const int a = blockIdx.y;
  const int t = threadIdx.x;
  const float rn = rnorm[a];
  const float* row = atoms + (size_t)a * LFREQ;
  unsigned short* hrow = anH + (size_t)a * KPS;
  unsigned short* lrow = anL + (size_t)a * KPS;
  const int c0 = quarter * 1040;
  const int c1 = min(c0 + 1040, KPS / 8);
  for (int c = c0 + t; c < c1; c += 256) {
    const int k0 = c * 8;
    float v[8];
    if (k0 + 8 <= LFREQ) {
      #pragma unroll
      for (int e = 0; e < 4; ++e) {
        const float2 p = *(const float2*)(row + k0 + 2 * e);
        v[2 * e] = p.x; v[2 * e + 1] = p.y;
      }
    } else {
      #pragma unroll
      for (int e = 0; e < 8; ++e) v[e] = (k0 + e < LFREQ) ? row[k0 + e] : 0.f;
    }
    u16x8 hv, lv;
    #pragma unroll
    for (int e = 0; e < 8; ++e) {
      const float sv = v[e] * rn;
      const unsigned short h = f2bf(sv);
      hv[e] = h;
      lv[e] = f2bf(sv - bf2f(h));
    }
    *(u16x8*)(hrow + k0) = hv;
    *(u16x8*)(lrow + k0) = lv;
  }
}

// ---------------- initial res -> bf16 hi/lo ----------------
__global__ __launch_bounds__(256) void res_convert_kernel(const float* __restrict__ res,
                                                          unsigned short* __restrict__ resH,
                                                          unsigned short* __restrict__ resL) {
  const int b = blockIdx.x, t = threadIdx.x;
  const float* row = res + (size_t)b * RSTR;
  unsigned short* hrow = resH + (size_t)b * KPS;
  unsigned short* lrow = resL + (size_t)b * KPS;
  for (int c = t; c < KPS / 8; c += 256) {
    const int k0 = c * 8;
    float v[8];
    if (k0 + 8 <= LFREQ) {
      #pragma unroll
      for (int e = 0; e < 2; ++e) {
        const float4 p = *(const float4*)(row + k0 + 4 * e);
        v[4 * e] = p.x; v[4 * e + 1] = p.y; v[4 * e + 2] = p.z; v[4 * e + 3] = p.w;
      }
    } else {
      #pragma unroll
      for (int e = 0; e < 8; ++e) v[e] = (k0 + e < LFREQ) ? row[k0 + e] : 0.f;
    }
    u16x8 hv, lv;
    #pragma unroll
    for (int e = 0; e < 8; ++e) {
      const unsigned short h = f2bf(v[e]);
      hv[e] = h;
      lv[e] = f2bf(v[e] - bf2f(h));
    }
    *(u16x8*)(hrow + k0) = hv;
    *(u16x8*)(lrow + k0) = lv;
  }
}

// ---------------- dots via split-bf16 MFMA with global_load_lds double-buffered staging ----
// partials[s][b][a] = sum_{k in slice s} res[b][k] * an[a][k]
// LDS is written in MFMA-fragment order (linear dest, per-lane pre-swizzled global source),
// so compute reads are conflict-free ds_read_b128 at base + lane*16.
// Waves split the 64x64 output 2x2; no cross-wave reduce.
__global__ __launch_bounds__(256) void dots_mfma_kernel(const unsigned short* __restrict__ resH,
                                                        const unsigned short* __restrict__ resL,
                                                        const unsigned short* __restrict__ anH,
                                                        const unsigned short* __restrict__ anL,
                                                        float* __restrict__ partials) {
  __shared__ char smem[65536];   // 2 x 32KB: [buf][AH 8K | AL 8K | BH 8K | BL 8K]
  const int slice = blockIdx.x;  // 0..NSLICE-1, K = 512 per block, chunks of 64
  const int atile = blockIdx.y;  // 0..7, 64 atoms each
  const int t = threadIdx.x;
  const int w = t >> 6, l = t & 63;
  const int bh = w >> 1, ah = w & 1;        // wave's output quadrant (32b x 32a)
  const int kc0 = slice * 512;

  // staging: wave w stages section w: 0=A-H(res), 1=A-L, 2=B-H(an), 3=B-L
  const unsigned short* gtab = (w == 0) ? resH : (w == 1) ? resL : (w == 2) ? anH : anL;
  const int rowoff = (w >= 2) ? atile * 64 : 0;
  const int lrow = rowoff + (l & 15);       // +rt*16 per issue
  const int lkof = (l >> 4) * 8;            // +kk*32 per issue

  f32x4 acc00 = {0.f,0.f,0.f,0.f}, acc01 = acc00, acc10 = acc00, acc11 = acc00;

#define STAGE(cc, bb)                                                                     \
  {                                                                                       \
    const int kc = kc0 + (cc) * 64;                                                       \
    _Pragma("unroll")                                                                     \
    for (int s = 0; s < 8; ++s) {                                                         \
      const unsigned short* g = gtab + (size_t)(lrow + (s >> 1) * 16) * KPS               \
                                + kc + (s & 1) * 32 + lkof;                               \
      char* d = smem + (bb) * 32768 + w * 8192 + s * 1024;                                \
      __builtin_amdgcn_global_load_lds((const __attribute__((address_space(1))) void*)g,  \
                                       (__attribute__((address_space(3))) void*)d,        \
                                       16, 0, 0);                                         \
    }                                                                                     \
  }

#define COMPUTE(bb)                                                                       \
  {                                                                                       \
    const char* base = smem + (bb) * 32768;                                               \
    _Pragma("unroll")                                                                     \
    for (int kk = 0; kk < 2; ++kk) {                                                      \
      const bf16x8 aH0 = *(const bf16x8*)(base + ((bh * 2 + 0) * 2 + kk) * 1024 + l * 16);\
      const bf16x8 aH1 = *(const bf16x8*)(base + ((bh * 2 + 1) * 2 + kk) * 1024 + l * 16);\
      const bf16x8 aL0 = *(const bf16x8*)(base + 8192 + ((bh * 2 + 0) * 2 + kk) * 1024 + l * 16);\
      const bf16x8 aL1 = *(const bf16x8*)(base + 8192 + ((bh * 2 + 1) * 2 + kk) * 1024 + l * 16);\
      const bf16x8 bH0 = *(const bf16x8*)(base + 16384 + ((ah * 2 + 0) * 2 + kk) * 1024 + l * 16);\
      const bf16x8 bH1 = *(const bf16x8*)(base + 16384 + ((ah * 2 + 1) * 2 + kk) * 1024 + l * 16);\
      const bf16x8 bL0 = *(const bf16x8*)(base + 24576 + ((ah * 2 + 0) * 2 + kk) * 1024 + l * 16);\
      const bf16x8 bL1 = *(const bf16x8*)(base + 24576 + ((ah * 2 + 1) * 2 + kk) * 1024 + l * 16);\
      acc00 = __builtin_amdgcn_mfma_f32_16x16x32_bf16(aH0, bH0, acc00, 0, 0, 0);          \
      acc01 = __builtin_amdgcn_mfma_f32_16x16x32_bf16(aH0, bH1, acc01, 0, 0, 0);          \
      acc10 = __builtin_amdgcn_mfma_f32_16x16x32_bf16(aH1, bH0, acc10, 0, 0, 0);          \
      acc11 = __builtin_amdgcn_mfma_f32_16x16x32_bf16(aH1, bH1, acc11, 0, 0, 0);          \
      acc00 = __builtin_amdgcn_mfma_f32_16x16x32_bf16(aH0, bL0, acc00, 0, 0, 0);          \
      acc01 = __builtin_amdgcn_mfma_f32_16x16x32_bf16(aH0, bL1, acc01, 0, 0, 0);          \
      acc10 = __builtin_amdgcn_mfma_f32_16x16x32_bf16(aH1, bL0, acc10, 0, 0, 0);          \
      acc11 = __builtin_amdgcn_mfma_f32_16x16x32_bf16(aH1, bL1, acc11, 0, 0, 0);          \
      acc00 = __builtin_amdgcn_mfma_f32_16x16x32_bf16(aL0, bH0, acc00, 0, 0, 0);          \
      acc01 = __builtin_amdgcn_mfma_f32_16x16x32_bf16(aL0, bH1, acc01, 0, 0, 0);          \
      acc10 = __builtin_amdgcn_mfma_f32_16x16x32_bf16(aL1, bH0, acc10, 0, 0, 0);          \
      acc11 = __builtin_amdgcn_mfma_f32_16x16x32_bf16(aL1, bH1, acc11, 0, 0, 0);          \
    }                                                                                     \
  }

  STAGE(0, 0);
  asm volatile("s_waitcnt vmcnt(0)" ::: "memory");
  __syncthreads();
  int buf = 0;
  #pragma unroll 2
  for (int c = 0; c < 8; ++c) {
    if (c < 7) STAGE(c + 1, buf ^ 1);
    COMPUTE(buf);
    asm volatile("s_waitcnt vmcnt(0)" ::: "memory");
    __syncthreads();
    buf ^= 1;
  }
#undef STAGE
#undef COMPUTE

  // D layout: row=(lane>>4)*4+e (batch), col=lane&15 (atom)
  const int brow = bh * 32 + (l >> 4) * 4;
  const int acol = atile * 64 + ah * 32 + (l & 15);
  float* pp = partials + ((size_t)slice * NB + brow) * NA + acol;
  #pragma unroll
  for (int e = 0; e < 4; ++e) {
    pp[(size_t)e * NA]            = acc00[e];
    pp[(size_t)e * NA + 16]       = acc01[e];
    pp[(size_t)(16 + e) * NA]     = acc10[e];
    pp[(size_t)(16 + e) * NA + 16]= acc11[e];
  }
}

// ---------------- reduce partials over slices + argmax (once per batch) ----------------
__global__ __launch_bounds__(256) void reduce_argmax_kernel(const float* __restrict__ partials,
                                                            int* __restrict__ bestidx) {
  const int b = blockIdx.x, t = threadIdx.x;
  float d0 = 0.f, d1 = 0.f;
  for (int s = 0; s < NSLICE; ++s) {
    const float* p = partials + ((size_t)s * NB + b) * NA;
    d0 += p[t];
    d1 += p[t + 256];
  }
  float best = d0; int bi = t;
  if (d1 > best) { best = d1; bi = t + 256; }   // strict > keeps smaller index
  __shared__ float sv[256]; __shared__ int si[256];
  sv[t] = best; si[t] = bi; __syncthreads();
  for (int st = 128; st > 0; st >>= 1) {
    if (t < st) {
      const float v2 = sv[t + st]; const int i2 = si[t + st];
      if (v2 > sv[t] || (v2 == sv[t] && i2 < si[t])) { sv[t] = v2; si[t] = i2; }
    }
    __syncthreads();
  }
  if (t == 0) bestidx[b] = si[0];
}

// ---------------- res/rec update + res bf16 refresh (vectorized); final iter also writes out2 ----------------
__global__ __launch_bounds__(256) void update_kernel(float* __restrict__ res,
                                                     float* __restrict__ rec,
                                                     const float* __restrict__ atoms,
                                                     const float* __restrict__ rnorm,
                                                     const int* __restrict__ bestidx,
                                                     unsigned short* __restrict__ resH,
                                                     unsigned short* __restrict__ resL,
                                                     float* __restrict__ out2,
                                                     int final_out) {
  const int slice = blockIdx.x;   // 0..USLICE-1
  const int b = blockIdx.y;
  const int t = threadIdx.x;
  const int idx = bestidx[b];
  const float rn = rnorm[idx];
  const float* arow = atoms + (size_t)idx * LFREQ;
  float* rrow = res + (size_t)b * RSTR;
  float* crow = rec + (size_t)b * RSTR;
  unsigned short* hrow = resH + (size_t)b * KPS;
  unsigned short* lrow = resL + (size_t)b * KPS;
  float* orow = out2 + (size_t)b * LFREQ;
  const int c0 = slice * 513;
  const int c1 = min(c0 + 513, NCH);
  for (int c = c0 + t; c < c1; c += 256) {
    const int k0 = c * 8;
    if (k0 + 8 <= LFREQ) {
      float rv[8], av[8], cv[8];
      #pragma unroll
      for (int e = 0; e < 2; ++e) {
        const float4 q = *(const float4*)(rrow + k0 + 4 * e);
        rv[4 * e] = q.x; rv[4 * e + 1] = q.y; rv[4 * e + 2] = q.z; rv[4 * e + 3] = q.w;
        const float4 qc = *(const float4*)(crow + k0 + 4 * e);
        cv[4 * e] = qc.x; cv[4 * e + 1] = qc.y; cv[4 * e + 2] = qc.z; cv[4 * e + 3] = qc.w;
      }
      #pragma unroll
      for (int e = 0; e < 4; ++e) {
        const float2 p = *(const float2*)(arow + k0 + 2 * e);
        av[2 * e] = p.x; av[2 * e + 1] = p.y;
      }
      float nv[8];
      u16x8 hv, lv;
      #pragma unroll
      for (int e = 0; e < 8; ++e) {
        const float bx = av[e] * rn * rv[e];
        nv[e] = rv[e] - bx;
        cv[e] += bx;
        const unsigned short h = f2bf(nv[e]);
        hv[e] = h;
        lv[e] = f2bf(nv[e] - bf2f(h));
      }
      #pragma unroll
      for (int e = 0; e < 2; ++e) {
        *(float4*)(rrow + k0 + 4 * e) = make_float4(nv[4*e], nv[4*e+1], nv[4*e+2], nv[4*e+3]);
        *(float4*)(crow + k0 + 4 * e) = make_float4(cv[4*e], cv[4*e+1], cv[4*e+2], cv[4*e+3]);
      }
      *(u16x8*)(hrow + k0) = hv;
      *(u16x8*)(lrow + k0) = lv;
      if (final_out) {
        #pragma unroll
        for (int e = 0; e < 2; ++e)
          *(float4*)(orow + k0 + 4 * e) = make_float4(nv[4*e], nv[4*e+1], nv[4*e+2], nv[4*e+3]);
      }
    } else {
      for (int e = 0; e < 8; ++e) {
        const int k = k0 + e;
        if (k < LFREQ) {
          const float r = rrow[k], a = arow[k], cc = crow[k];
          const float bx = a * rn * r;
          const float nx = r - bx;
          rrow[k] = nx;
          crow[k] = cc + bx;
          const unsigned short h = f2bf(nx);
          hrow[k] = h;
          lrow[k] = f2bf(nx - bf2f(h));
          if (final_out) orow[k] = nx;
        }
      }
    }
  }
}

extern "C" void kernel_launch(void* const* d_in, const int* in_sizes, int n_in,
                              void* d_out, int out_size, void* d_ws, size_t ws_size,
                              hipStream_t stream) {
  const float* x = (const float*)d_in[0];      // (64,1,32768)
  const float* atoms = (const float*)d_in[1];  // (1,512,32770)
  float* out = (float*)d_out;

  float* res = (float*)d_ws;                             // 64*32772 f32
  float* rec = res + (size_t)NB * RSTR;                  // 64*32772 f32
  float* rnorm = rec + (size_t)NB * RSTR;                // 512
  float* partials = rnorm + NA;                          // 65*64*512 f32
  int* bestidx = (int*)(partials + (size_t)NSLICE * NB * NA);   // 64
  unsigned short* resH = (unsigned short*)(bestidx + 64);
  unsigned short* resL = resH + (size_t)NB * KPS;
  unsigned short* anH  = resL + (size_t)NB * KPS;
  unsigned short* anL  = anH + (size_t)NA * KPS;

  hipMemsetAsync(rec, 0, (size_t)NB * RSTR * sizeof(float), stream);
  atom_norm_kernel<<<NA, 256, 0, stream>>>(atoms, rnorm);
  an_bf16_kernel<<<dim3(4, NA), 256, 0, stream>>>(atoms, rnorm, anH, anL);
  fft_fwd_kernel<<<NB, 1024, MH * sizeof(float2), stream>>>(x, res);
  res_convert_kernel<<<NB, 256, 0, stream>>>(res, resH, resL);

  float* res_out = out + (size_t)NB * NSAMP;
  for (int it = 0; it < NITER; ++it) {
    dots_mfma_kernel<<<dim3(NSLICE, 8), 256, 0, stream>>>(resH, resL, anH, anL, partials);
    reduce_argmax_kernel<<<NB, 256, 0, stream>>>(partials, bestidx);
    update_kernel<<<dim3(USLICE, NB), 256, 0, stream>>>(res, rec, atoms, rnorm, bestidx,
                                                        resH, resL, res_out,
                                                        (it == NITER - 1) ? 1 : 0);
  }

  fft_inv_kernel<<<NB, 1024, MH * sizeof(float2), stream>>>(rec, out);
}

// Round 7
// 2901.268 us; speedup vs baseline: 1.3553x; 1.0778x over previous
//
#include <hip/hip_runtime.h>
#include <math.h>

#define NSAMP 32768      // time-domain samples
#define MH    16384      // half-size complex FFT length (= 4^7)
#define LFREQ 32770      // rfft concat(re,im) length = 2*(NSAMP/2+1)
#define NRE   16385      // number of rfft bins
#define NB    64         // batches
#define NA    512        // atoms
#define NITER 64
#define RSTR  32772      // padded row stride for fp32 res/rec in ws

#define KPS    33280     // bf16 row stride = 65*512 (zero-padded past LFREQ)
#define NSLICE 65        // k-slices for dots (512 k each)
#define USLICE 8         // update kernel k-split
#define NCH    4097      // ceil(LFREQ/8) 8-float chunks per row

typedef __attribute__((ext_vector_type(8))) short bf16x8;
typedef __attribute__((ext_vector_type(8))) unsigned short u16x8;
typedef __attribute__((ext_vector_type(4))) float f32x4;

// base-4 digit reversal of a 14-bit index (7 digits)
__device__ __forceinline__ int rev4_14(int v) {
  unsigned r = __brev((unsigned)v) >> 18;                     // 14-bit bit reversal
  r = ((r & 0x1555u) << 1) | ((r >> 1) & 0x1555u);            // swap bit pairs
  return (int)r;
}

__device__ __forceinline__ unsigned short f2bf(float f) {
  unsigned u = __float_as_uint(f);
  u = (u + 0x7fffu + ((u >> 16) & 1u)) >> 16;   // round-to-nearest-even
  return (unsigned short)u;
}
__device__ __forceinline__ float bf2f(unsigned short h) {
  return __uint_as_float(((unsigned)h) << 16);
}

__device__ __forceinline__ float2 cmul(float2 a, float2 b) {
  return make_float2(a.x * b.x - a.y * b.y, a.x * b.y + a.y * b.x);
}

// ---------------- forward rfft: x[b][32768] -> res[b][32770] (re|im concat) ----------------
__global__ __launch_bounds__(1024) void fft_fwd_kernel(const float* __restrict__ x,
                                                       float* __restrict__ res) {
  extern __shared__ float2 s[];   // 16384 complex = 128 KB
  const int b = blockIdx.x, t = threadIdx.x;
  const float2* xrow = (const float2*)(x + (size_t)b * NSAMP);
  // pack z[m] = x[2m] + i x[2m+1]; base-4 digit-reverse on the READ side
  for (int m = t; m < MH; m += 1024) s[m] = xrow[rev4_14(m)];
  __syncthreads();
  // 7 radix-4 DIT stages, twiddle e^{-i*2pi*pos/len}
  for (int st = 0; st < 7; ++st) {
    const int q = 1 << (2 * st);
    const float fac = 6.283185307179586f / (float)(4 * q);
    for (int j = t; j < MH / 4; j += 1024) {
      const int blk = j >> (2 * st), pos = j & (q - 1);
      const int i0 = (blk << (2 * st + 2)) + pos;
      float sn, cs; __sincosf(fac * (float)pos, &sn, &cs);
      const float2 w1 = make_float2(cs, -sn);
      const float2 w2 = cmul(w1, w1);
      const float2 w3 = cmul(w2, w1);
      const float2 a0 = s[i0], a1 = s[i0 + q], a2 = s[i0 + 2 * q], a3 = s[i0 + 3 * q];
      const float2 x1 = cmul(w1, a1), x2 = cmul(w2, a2), x3 = cmul(w3, a3);
      const float2 s0 = make_float2(a0.x + x2.x, a0.y + x2.y);
      const float2 s1 = make_float2(a0.x - x2.x, a0.y - x2.y);
      const float2 t0 = make_float2(x1.x + x3.x, x1.y + x3.y);
      const float2 t1 = make_float2(x1.x - x3.x, x1.y - x3.y);
      s[i0]         = make_float2(s0.x + t0.x, s0.y + t0.y);
      s[i0 + q]     = make_float2(s1.x + t1.y, s1.y - t1.x);   // s1 - i*t1
      s[i0 + 2 * q] = make_float2(s0.x - t0.x, s0.y - t0.y);
      s[i0 + 3 * q] = make_float2(s1.x - t1.y, s1.y + t1.x);   // s1 + i*t1
    }
    __syncthreads();
  }
  // unpack half-size FFT -> rfft bins
  float* rr = res + (size_t)b * RSTR;
  const float fac2 = 6.283185307179586f / (float)NSAMP;
  for (int k = t; k < MH; k += 1024) {
    if (k == 0) {
      const float2 z0 = s[0];
      rr[0] = z0.x + z0.y;      rr[NRE] = 0.f;
      rr[MH] = z0.x - z0.y;     rr[NRE + MH] = 0.f;
    } else {
      const float2 zk = s[k], zm = s[MH - k];
      const float xer = 0.5f * (zk.x + zm.x), xei = 0.5f * (zk.y - zm.y);
      const float p = 0.5f * (zk.y + zm.y);
      const float q = -0.5f * (zk.x - zm.x);
      float sn, cs; __sincosf(fac2 * (float)k, &sn, &cs);
      rr[k]       = xer + cs * p + sn * q;
      rr[NRE + k] = xei + cs * q - sn * p;
    }
  }
}

// ---------------- inverse rfft: rec[b][32770] -> out[b][32768] ----------------
__global__ __launch_bounds__(1024) void fft_inv_kernel(const float* __restrict__ rec,
                                                       float* __restrict__ out) {
  extern __shared__ float2 s[];
  const int b = blockIdx.x, t = threadIdx.x;
  const float* rr = rec + (size_t)b * RSTR;
  const float fac2 = 6.283185307179586f / (float)NSAMP;
  for (int m = t; m < MH; m += 1024) {
    const int k = rev4_14(m);
    float2 z;
    if (k == 0) {
      const float a0 = rr[0], aM = rr[MH];   // c2r ignores imag of DC & Nyquist
      z = make_float2(0.5f * (a0 + aM), 0.5f * (a0 - aM));
    } else {
      const float xr_ = rr[k],       xi_ = rr[NRE + k];
      const float mr  = rr[MH - k],  mi  = rr[NRE + MH - k];
      const float xer = 0.5f * (xr_ + mr), xei = 0.5f * (xi_ - mi);
      const float er  = 0.5f * (xr_ - mr), ei  = 0.5f * (xi_ + mi);
      float sn, cs; __sincosf(fac2 * (float)k, &sn, &cs);
      const float xor_ = cs * er - sn * ei;
      const float xoi  = cs * ei + sn * er;
      z = make_float2(xer - xoi, xei + xor_);
    }
    s[m] = z;
  }
  __syncthreads();
  // 7 radix-4 DIT stages, twiddle e^{+i*2pi*pos/len}
  for (int st = 0; st < 7; ++st) {
    const int q = 1 << (2 * st);
    const float fac = 6.283185307179586f / (float)(4 * q);
    for (int j = t; j < MH / 4; j += 1024) {
      const int blk = j >> (2 * st), pos = j & (q - 1);
      const int i0 = (blk << (2 * st + 2)) + pos;
      float sn, cs; __sincosf(fac * (float)pos, &sn, &cs);
      const float2 w1 = make_float2(cs, sn);
      const float2 w2 = cmul(w1, w1);
      const float2 w3 = cmul(w2, w1);
      const float2 a0 = s[i0], a1 = s[i0 + q], a2 = s[i0 + 2 * q], a3 = s[i0 + 3 * q];
      const float2 x1 = cmul(w1, a1), x2 = cmul(w2, a2), x3 = cmul(w3, a3);
      const float2 s0 = make_float2(a0.x + x2.x, a0.y + x2.y);
      const float2 s1 = make_float2(a0.x - x2.x, a0.y - x2.y);
      const float2 t0 = make_float2(x1.x + x3.x, x1.y + x3.y);
      const float2 t1 = make_float2(x1.x - x3.x, x1.y - x3.y);
      s[i0]         = make_float2(s0.x + t0.x, s0.y + t0.y);
      s[i0 + q]     = make_float2(s1.x - t1.y, s1.y + t1.x);   // s1 + i*t1
      s[i0 + 2 * q] = make_float2(s0.x - t0.x, s0.y - t0.y);
      s[i0 + 3 * q] = make_float2(s1.x + t1.y, s1.y - t1.x);   // s1 - i*t1
    }
    __syncthreads();
  }
  const float inv = 1.0f / (float)MH;
  float2* orow = (float2*)(out + (size_t)b * NSAMP);
  for (int m = t; m < MH; m += 1024) {
    const float2 z = s[m];
    orow[m] = make_float2(z.x * inv, z.y * inv);
  }
}

// ---------------- atom norms: rnorm[a] = 1/||atoms[a]|| ----------------
__global__ __launch_bounds__(256) void atom_norm_kernel(const float* __restrict__ atoms,
                                                        float* __restrict__ rnorm) {
  const int a = blockIdx.x, t = threadIdx.x;
  const float2* row2 = (const float2*)(atoms + (size_t)a * LFREQ);
  float ss = 0.f;
  for (int i = t; i < LFREQ / 2; i += 256) {   // 16385 float2 exactly
    const float2 v = row2[i];
    ss += v.x * v.x + v.y * v.y;
  }
  __shared__ float red[256];
  red[t] = ss; __syncthreads();
  for (int st = 128; st > 0; st >>= 1) {
    if (t < st) red[t] += red[t + st];
    __syncthreads();
  }
  if (t == 0) rnorm[a] = 1.0f / sqrtf(red[0]);
}

// ---------------- normalized atoms -> bf16 hi/lo (rnorm folded in), big grid ----------------
__global__ __launch_bounds__(256) void an_bf16_kernel(const float* __restrict__ atoms,
                                                      const float* __restrict__ rnorm,
                                                      unsigned short* __restrict__ anH,
                                                      unsigned short* __restrict__ anL) {
  const int quarter = blockIdx.x;   // 0..3
  const int a = blockIdx.y;
  const int t = threadIdx.x;
  const float rn = rnorm[a];
  const float* row = atoms + (size_t)a * LFREQ;
  unsigned short* hrow = anH + (size_t)a * KPS;
  unsigned short* lrow = anL + (size_t)a * KPS;
  const int c0 = quarter * 1040;
  const int c1 = min(c0 + 1040, KPS / 8);
  for (int c = c0 + t; c < c1; c += 256) {
    const int k0 = c * 8;
    float v[8];
    if (k0 + 8 <= LFREQ) {
      #pragma unroll
      for (int e = 0; e < 4; ++e) {
        const float2 p = *(const float2*)(row + k0 + 2 * e);
        v[2 * e] = p.x; v[2 * e + 1] = p.y;
      }
    } else {
      #pragma unroll
      for (int e = 0; e < 8; ++e) v[e] = (k0 + e < LFREQ) ? row[k0 + e] : 0.f;
    }
    u16x8 hv, lv;
    #pragma unroll
    for (int e = 0; e < 8; ++e) {
      const float sv = v[e] * rn;
      const unsigned short h = f2bf(sv);
      hv[e] = h;
      lv[e] = f2bf(sv - bf2f(h));
    }
    *(u16x8*)(hrow + k0) = hv;
    *(u16x8*)(lrow + k0) = lv;
  }
}

// ---------------- initial res -> bf16 hi/lo ----------------
__global__ __launch_bounds__(256) void res_convert_kernel(const float* __restrict__ res,
                                                          unsigned short* __restrict__ resH,
                                                          unsigned short* __restrict__ resL) {
  const int b = blockIdx.x, t = threadIdx.x;
  const float* row = res + (size_t)b * RSTR;
  unsigned short* hrow = resH + (size_t)b * KPS;
  unsigned short* lrow = resL + (size_t)b * KPS;
  for (int c = t; c < KPS / 8; c += 256) {
    const int k0 = c * 8;
    float v[8];
    if (k0 + 8 <= LFREQ) {
      #pragma unroll
      for (int e = 0; e < 2; ++e) {
        const float4 p = *(const float4*)(row + k0 + 4 * e);
        v[4 * e] = p.x; v[4 * e + 1] = p.y; v[4 * e + 2] = p.z; v[4 * e + 3] = p.w;
      }
    } else {
      #pragma unroll
      for (int e = 0; e < 8; ++e) v[e] = (k0 + e < LFREQ) ? row[k0 + e] : 0.f;
    }
    u16x8 hv, lv;
    #pragma unroll
    for (int e = 0; e < 8; ++e) {
      const unsigned short h = f2bf(v[e]);
      hv[e] = h;
      lv[e] = f2bf(v[e] - bf2f(h));
    }
    *(u16x8*)(hrow + k0) = hv;
    *(u16x8*)(lrow + k0) = lv;
  }
}

// ---------------- dots via split-bf16 MFMA, gload_lds staging, counted-vmcnt pipeline ----
// partials[b][s][a] = sum_{k in slice s} res[b][k] * an[a][k]
__global__ __launch_bounds__(256) void dots_mfma_kernel(const unsigned short* __restrict__ resH,
                                                        const unsigned short* __restrict__ resL,
                                                        const unsigned short* __restrict__ anH,
                                                        const unsigned short* __restrict__ anL,
                                                        float* __restrict__ partials) {
  __shared__ char smem[65536];   // 2 x 32KB: [buf][AH 8K | AL 8K | BH 8K | BL 8K]
  const int slice = blockIdx.x;  // 0..NSLICE-1, K = 512 per block, chunks of 64
  const int atile = blockIdx.y;  // 0..7, 64 atoms each
  const int t = threadIdx.x;
  const int w = t >> 6, l = t & 63;
  const int bh = w >> 1, ah = w & 1;        // wave's output quadrant (32b x 32a)
  const int kc0 = slice * 512;

  // staging: wave w stages section w: 0=A-H(res), 1=A-L, 2=B-H(an), 3=B-L
  const unsigned short* gtab = (w == 0) ? resH : (w == 1) ? resL : (w == 2) ? anH : anL;
  const int rowoff = (w >= 2) ? atile * 64 : 0;
  const int lrow = rowoff + (l & 15);       // +rt*16 per issue
  const int lkof = (l >> 4) * 8;            // +kk*32 per issue

  f32x4 acc00 = {0.f,0.f,0.f,0.f}, acc01 = acc00, acc10 = acc00, acc11 = acc00;

#define STAGE(cc, bb)                                                                     \
  {                                                                                       \
    const int kc = kc0 + (cc) * 64;                                                       \
    _Pragma("unroll")                                                                     \
    for (int si = 0; si < 8; ++si) {                                                      \
      const unsigned short* g = gtab + (size_t)(lrow + (si >> 1) * 16) * KPS              \
                                + kc + (si & 1) * 32 + lkof;                              \
      char* d = smem + (bb) * 32768 + w * 8192 + si * 1024;                               \
      __builtin_amdgcn_global_load_lds((const __attribute__((address_space(1))) void*)g,  \
                                       (__attribute__((address_space(3))) void*)d,        \
                                       16, 0, 0);                                         \
    }                                                                                     \
  }

#define COMPUTE(bb)                                                                       \
  {                                                                                       \
    const char* base = smem + (bb) * 32768;                                               \
    _Pragma("unroll")                                                                     \
    for (int kk = 0; kk < 2; ++kk) {                                                      \
      const bf16x8 aH0 = *(const bf16x8*)(base + ((bh * 2 + 0) * 2 + kk) * 1024 + l * 16);\
      const bf16x8 aH1 = *(const bf16x8*)(base + ((bh * 2 + 1) * 2 + kk) * 1024 + l * 16);\
      const bf16x8 aL0 = *(const bf16x8*)(base + 8192 + ((bh * 2 + 0) * 2 + kk) * 1024 + l * 16);\
      const bf16x8 aL1 = *(const bf16x8*)(base + 8192 + ((bh * 2 + 1) * 2 + kk) * 1024 + l * 16);\
      const bf16x8 bH0 = *(const bf16x8*)(base + 16384 + ((ah * 2 + 0) * 2 + kk) * 1024 + l * 16);\
      const bf16x8 bH1 = *(const bf16x8*)(base + 16384 + ((ah * 2 + 1) * 2 + kk) * 1024 + l * 16);\
      const bf16x8 bL0 = *(const bf16x8*)(base + 24576 + ((ah * 2 + 0) * 2 + kk) * 1024 + l * 16);\
      const bf16x8 bL1 = *(const bf16x8*)(base + 24576 + ((ah * 2 + 1) * 2 + kk) * 1024 + l * 16);\
      acc00 = __builtin_amdgcn_mfma_f32_16x16x32_bf16(aH0, bH0, acc00, 0, 0, 0);          \
      acc01 = __builtin_amdgcn_mfma_f32_16x16x32_bf16(aH0, bH1, acc01, 0, 0, 0);          \
      acc10 = __builtin_amdgcn_mfma_f32_16x16x32_bf16(aH1, bH0, acc10, 0, 0, 0);          \
      acc11 = __builtin_amdgcn_mfma_f32_16x16x32_bf16(aH1, bH1, acc11, 0, 0, 0);          \
      acc00 = __builtin_amdgcn_mfma_f32_16x16x32_bf16(aH0, bL0, acc00, 0, 0, 0);          \
      acc01 = __builtin_amdgcn_mfma_f32_16x16x32_bf16(aH0, bL1, acc01, 0, 0, 0);          \
      acc10 = __builtin_amdgcn_mfma_f32_16x16x32_bf16(aH1, bL0, acc10, 0, 0, 0);          \
      acc11 = __builtin_amdgcn_mfma_f32_16x16x32_bf16(aH1, bL1, acc11, 0, 0, 0);          \
      acc00 = __builtin_amdgcn_mfma_f32_16x16x32_bf16(aL0, bH0, acc00, 0, 0, 0);          \
      acc01 = __builtin_amdgcn_mfma_f32_16x16x32_bf16(aL0, bH1, acc01, 0, 0, 0);          \
      acc10 = __builtin_amdgcn_mfma_f32_16x16x32_bf16(aL1, bH0, acc10, 0, 0, 0);          \
      acc11 = __builtin_amdgcn_mfma_f32_16x16x32_bf16(aL1, bH1, acc11, 0, 0, 0);          \
    }                                                                                     \
  }

  STAGE(0, 0);
  #pragma unroll
  for (int c = 0; c < 8; ++c) {
    const int buf = c & 1;
    if (c < 7) {
      STAGE(c + 1, buf ^ 1);
      asm volatile("s_waitcnt vmcnt(8)" ::: "memory");   // oldest 8 (chunk c) complete
    } else {
      asm volatile("s_waitcnt vmcnt(0)" ::: "memory");
    }
    __builtin_amdgcn_s_barrier();            // chunk c visible to all waves
    __builtin_amdgcn_sched_barrier(0);
    COMPUTE(buf);
    __builtin_amdgcn_sched_barrier(0);
    __builtin_amdgcn_s_barrier();            // all waves done reading buf before re-stage
  }
#undef STAGE
#undef COMPUTE

  // D layout: row=(lane>>4)*4+e (batch), col=lane&15 (atom); partials is [b][s][a]
  const int brow = bh * 32 + (l >> 4) * 4;
  const int acol = atile * 64 + ah * 32 + (l & 15);
  float* pp = partials + ((size_t)brow * NSLICE + slice) * NA + acol;
  const size_t bstr = (size_t)NSLICE * NA;
  #pragma unroll
  for (int e = 0; e < 4; ++e) {
    pp[(size_t)e * bstr]             = acc00[e];
    pp[(size_t)e * bstr + 16]        = acc01[e];
    pp[(size_t)(16 + e) * bstr]      = acc10[e];
    pp[(size_t)(16 + e) * bstr + 16] = acc11[e];
  }
}

// ---------------- reduce partials over slices + argmax (once per batch) ----------------
__global__ __launch_bounds__(256) void reduce_argmax_kernel(const float* __restrict__ partials,
                                                            int* __restrict__ bestidx) {
  const int b = blockIdx.x, t = threadIdx.x;
  const float* pb = partials + (size_t)b * NSLICE * NA;   // contiguous 133 KB per batch
  float d0 = 0.f, d1 = 0.f;
  #pragma unroll 13
  for (int s = 0; s < NSLICE; ++s) {
    d0 += pb[(size_t)s * NA + t];
    d1 += pb[(size_t)s * NA + t + 256];
  }
  float best = d0; int bi = t;
  if (d1 > best) { best = d1; bi = t + 256; }   // strict > keeps smaller index
  __shared__ float sv[256]; __shared__ int si[256];
  sv[t] = best; si[t] = bi; __syncthreads();
  for (int st = 128; st > 0; st >>= 1) {
    if (t < st) {
      const float v2 = sv[t + st]; const int i2 = si[t + st];
      if (v2 > sv[t] || (v2 == sv[t] && i2 < si[t])) { sv[t] = v2; si[t] = i2; }
    }
    __syncthreads();
  }
  if (t == 0) bestidx[b] = si[0];
}

// ---------------- res/rec update + res bf16 refresh (vectorized); final iter also writes out2 ----------------
__global__ __launch_bounds__(256) void update_kernel(float* __restrict__ res,
                                                     float* __restrict__ rec,
                                                     const float* __restrict__ atoms,
                                                     const float* __restrict__ rnorm,
                                                     const int* __restrict__ bestidx,
                                                     unsigned short* __restrict__ resH,
                                                     unsigned short* __restrict__ resL,
                                                     float* __restrict__ out2,
                                                     int final_out) {
  const int slice = blockIdx.x;   // 0..USLICE-1
  const int b = blockIdx.y;
  const int t = threadIdx.x;
  const int idx = bestidx[b];
  const float rn = rnorm[idx];
  const float* arow = atoms + (size_t)idx * LFREQ;
  float* rrow = res + (size_t)b * RSTR;
  float* crow = rec + (size_t)b * RSTR;
  unsigned short* hrow = resH + (size_t)b * KPS;
  unsigned short* lrow = resL + (size_t)b * KPS;
  float* orow = out2 + (size_t)b * LFREQ;
  const int c0 = slice * 513;
  const int c1 = min(c0 + 513, NCH);
  for (int c = c0 + t; c < c1; c += 256) {
    const int k0 = c * 8;
    if (k0 + 8 <= LFREQ) {
      float rv[8], av[8], cv[8];
      #pragma unroll
      for (int e = 0; e < 2; ++e) {
        const float4 q = *(const float4*)(rrow + k0 + 4 * e);
        rv[4 * e] = q.x; rv[4 * e + 1] = q.y; rv[4 * e + 2] = q.z; rv[4 * e + 3] = q.w;
        const float4 qc = *(const float4*)(crow + k0 + 4 * e);
        cv[4 * e] = qc.x; cv[4 * e + 1] = qc.y; cv[4 * e + 2] = qc.z; cv[4 * e + 3] = qc.w;
      }
      #pragma unroll
      for (int e = 0; e < 4; ++e) {
        const float2 p = *(const float2*)(arow + k0 + 2 * e);
        av[2 * e] = p.x; av[2 * e + 1] = p.y;
      }
      float nv[8];
      u16x8 hv, lv;
      #pragma unroll
      for (int e = 0; e < 8; ++e) {
        const float bx = av[e] * rn * rv[e];
        nv[e] = rv[e] - bx;
        cv[e] += bx;
        const unsigned short h = f2bf(nv[e]);
        hv[e] = h;
        lv[e] = f2bf(nv[e] - bf2f(h));
      }
      #pragma unroll
      for (int e = 0; e < 2; ++e) {
        *(float4*)(rrow + k0 + 4 * e) = make_float4(nv[4*e], nv[4*e+1], nv[4*e+2], nv[4*e+3]);
        *(float4*)(crow + k0 + 4 * e) = make_float4(cv[4*e], cv[4*e+1], cv[4*e+2], cv[4*e+3]);
      }
      *(u16x8*)(hrow + k0) = hv;
      *(u16x8*)(lrow + k0) = lv;
      if (final_out) {
        #pragma unroll
        for (int e = 0; e < 2; ++e)
          *(float4*)(orow + k0 + 4 * e) = make_float4(nv[4*e], nv[4*e+1], nv[4*e+2], nv[4*e+3]);
      }
    } else {
      for (int e = 0; e < 8; ++e) {
        const int k = k0 + e;
        if (k < LFREQ) {
          const float r = rrow[k], a = arow[k], cc = crow[k];
          const float bx = a * rn * r;
          const float nx = r - bx;
          rrow[k] = nx;
          crow[k] = cc + bx;
          const unsigned short h = f2bf(nx);
          hrow[k] = h;
          lrow[k] = f2bf(nx - bf2f(h));
          if (final_out) orow[k] = nx;
        }
      }
    }
  }
}

extern "C" void kernel_launch(void* const* d_in, const int* in_sizes, int n_in,
                              void* d_out, int out_size, void* d_ws, size_t ws_size,
                              hipStream_t stream) {
  const float* x = (const float*)d_in[0];      // (64,1,32768)
  const float* atoms = (const float*)d_in[1];  // (1,512,32770)
  float* out = (float*)d_out;

  float* res = (float*)d_ws;                             // 64*32772 f32
  float* rec = res + (size_t)NB * RSTR;                  // 64*32772 f32
  float* rnorm = rec + (size_t)NB * RSTR;                // 512
  float* partials = rnorm + NA;                          // 64*65*512 f32  [b][s][a]
  int* bestidx = (int*)(partials + (size_t)NB * NSLICE * NA);   // 64
  unsigned short* resH = (unsigned short*)(bestidx + 64);
  unsigned short* resL = resH + (size_t)NB * KPS;
  unsigned short* anH  = resL + (size_t)NB * KPS;
  unsigned short* anL  = anH + (size_t)NA * KPS;

  hipMemsetAsync(rec, 0, (size_t)NB * RSTR * sizeof(float), stream);
  atom_norm_kernel<<<NA, 256, 0, stream>>>(atoms, rnorm);
  an_bf16_kernel<<<dim3(4, NA), 256, 0, stream>>>(atoms, rnorm, anH, anL);
  fft_fwd_kernel<<<NB, 1024, MH * sizeof(float2), stream>>>(x, res);
  res_convert_kernel<<<NB, 256, 0, stream>>>(res, resH, resL);

  float* res_out = out + (size_t)NB * NSAMP;
  for (int it = 0; it < NITER; ++it) {
    dots_mfma_kernel<<<dim3(NSLICE, 8), 256, 0, stream>>>(resH, resL, anH, anL, partials);
    reduce_argmax_kernel<<<NB, 256, 0, stream>>>(partials, bestidx);
    update_kernel<<<dim3(USLICE, NB), 256, 0, stream>>>(res, rec, atoms, rnorm, bestidx,
                                                        resH, resL, res_out,
                                                        (it == NITER - 1) ? 1 : 0);
  }

  fft_inv_kernel<<<NB, 1024, MH * sizeof(float2), stream>>>(rec, out);
}